// Round 1
// baseline (692.877 us; speedup 1.0000x reference)
//
#include <hip/hip_runtime.h>
#include <hip/hip_bf16.h>
#include <stdint.h>

#define DIM 2048
#define HID 5632
#define BM 128
#define BN 128
#define BK 32

typedef __attribute__((ext_vector_type(8))) short short8;
typedef __attribute__((ext_vector_type(4))) float f32x4;
typedef __attribute__((ext_vector_type(4))) int int4v;
typedef __attribute__((ext_vector_type(4))) unsigned short ushort4v;

__device__ __forceinline__ unsigned short f32_to_bf16_rne(float f) {
    union { float f; unsigned u; } v; v.f = f;
    unsigned u = v.u;
    return (unsigned short)((u + 0x7FFFu + ((u >> 16) & 1u)) >> 16);
}

__device__ __forceinline__ void gload16(const void* g, void* l) {
    __builtin_amdgcn_global_load_lds(
        (const __attribute__((address_space(1))) void*)g,
        (__attribute__((address_space(3))) void*)l,
        16, 0, 0);
}

// ---- dequant: bf16_out[i] = (wq[i] - 128) * scale[i / cols] ----
__global__ void dequant_bf16(const int* __restrict__ wq, const float* __restrict__ scale,
                             unsigned short* __restrict__ out, long total, int cols) {
    long n4 = total >> 2;
    long stride = (long)gridDim.x * blockDim.x;
    for (long i = (long)blockIdx.x * blockDim.x + threadIdx.x; i < n4; i += stride) {
        int4v c = ((const int4v*)wq)[i];
        int row = (int)((i << 2) / cols);
        float s = scale[row];
        ushort4v o;
        o.x = f32_to_bf16_rne(((float)c.x - 128.0f) * s);
        o.y = f32_to_bf16_rne(((float)c.y - 128.0f) * s);
        o.z = f32_to_bf16_rne(((float)c.z - 128.0f) * s);
        o.w = f32_to_bf16_rne(((float)c.w - 128.0f) * s);
        ((ushort4v*)out)[i] = o;
    }
}

// ---- x: f32 -> bf16 ----
__global__ void cast_f32_bf16(const float* __restrict__ in, unsigned short* __restrict__ out, long n) {
    long n4 = n >> 2;
    long stride = (long)gridDim.x * blockDim.x;
    for (long i = (long)blockIdx.x * blockDim.x + threadIdx.x; i < n4; i += stride) {
        f32x4 v = ((const f32x4*)in)[i];
        ushort4v o;
        o.x = f32_to_bf16_rne(v[0]);
        o.y = f32_to_bf16_rne(v[1]);
        o.z = f32_to_bf16_rne(v[2]);
        o.w = f32_to_bf16_rne(v[3]);
        ((ushort4v*)out)[i] = o;
    }
}

// ---- fused gate+up GEMM: h = silu(x@Wg^T) * (x@Wu^T), bf16 out ----
// X [M][DIM] bf16, Wg/Wu [HID][DIM] bf16, H [M][HID] bf16
__global__ __launch_bounds__(256, 2) void gemm_gateup(
    const unsigned short* __restrict__ X,
    const unsigned short* __restrict__ Wg,
    const unsigned short* __restrict__ Wu,
    unsigned short* __restrict__ H, int M)
{
    __shared__ __attribute__((aligned(16))) unsigned short As[BM * BK];
    __shared__ __attribute__((aligned(16))) unsigned short Bgs[BN * BK];
    __shared__ __attribute__((aligned(16))) unsigned short Bus[BN * BK];

    const int tid  = threadIdx.x;
    const int lane = tid & 63;
    const int wid  = tid >> 6;
    const int wr   = wid >> 1, wc = wid & 1;
    const int m0 = blockIdx.x * BM;
    const int n0 = blockIdx.y * BN;

    // staging geometry: chunk idx in [0,512): row = idx>>2, col8 = (idx&3)*8
    const int idx0 = tid, idx1 = tid + 256;
    const int r0 = idx0 >> 2, c0 = (idx0 & 3) << 3;
    const int r1 = idx1 >> 2, c1 = (idx1 & 3) << 3;

    const unsigned short* A0 = X  + (size_t)(m0 + r0) * DIM + c0;
    const unsigned short* A1 = X  + (size_t)(m0 + r1) * DIM + c1;
    const unsigned short* G0 = Wg + (size_t)(n0 + r0) * DIM + c0;
    const unsigned short* G1 = Wg + (size_t)(n0 + r1) * DIM + c1;
    const unsigned short* U0 = Wu + (size_t)(n0 + r0) * DIM + c0;
    const unsigned short* U1 = Wu + (size_t)(n0 + r1) * DIM + c1;

    f32x4 accg[4][4] = {};
    f32x4 accu[4][4] = {};

    const int lr = lane & 15;
    const int kr = (lane >> 4) << 3;

    for (int k0 = 0; k0 < DIM; k0 += BK) {
        gload16(A0 + k0, &As[idx0 * 8]);
        gload16(A1 + k0, &As[idx1 * 8]);
        gload16(G0 + k0, &Bgs[idx0 * 8]);
        gload16(G1 + k0, &Bgs[idx1 * 8]);
        gload16(U0 + k0, &Bus[idx0 * 8]);
        gload16(U1 + k0, &Bus[idx1 * 8]);
        __syncthreads();

        short8 a[4], bg[4], bu[4];
        #pragma unroll
        for (int i = 0; i < 4; ++i)
            a[i] = *(const short8*)&As[(wr * 64 + i * 16 + lr) * BK + kr];
        #pragma unroll
        for (int i = 0; i < 4; ++i)
            bg[i] = *(const short8*)&Bgs[(wc * 64 + i * 16 + lr) * BK + kr];
        #pragma unroll
        for (int i = 0; i < 4; ++i)
            bu[i] = *(const short8*)&Bus[(wc * 64 + i * 16 + lr) * BK + kr];

        #pragma unroll
        for (int i = 0; i < 4; ++i) {
            #pragma unroll
            for (int j = 0; j < 4; ++j) {
                accg[i][j] = __builtin_amdgcn_mfma_f32_16x16x32_bf16(a[i], bg[j], accg[i][j], 0, 0, 0);
                accu[i][j] = __builtin_amdgcn_mfma_f32_16x16x32_bf16(a[i], bu[j], accu[i][j], 0, 0, 0);
            }
        }
        __syncthreads();
    }

    const int lg = lane >> 4;
    #pragma unroll
    for (int i = 0; i < 4; ++i) {
        #pragma unroll
        for (int j = 0; j < 4; ++j) {
            #pragma unroll
            for (int e = 0; e < 4; ++e) {
                int row = m0 + wr * 64 + i * 16 + lg * 4 + e;
                int col = n0 + wc * 64 + j * 16 + lr;
                float g = accg[i][j][e];
                float u = accu[i][j][e];
                float sg = g / (1.0f + __expf(-g));
                H[(size_t)row * HID + col] = f32_to_bf16_rne(sg * u);
            }
        }
    }
}

// ---- down GEMM: out = h @ Wd^T, f32 out ----
// Hb [M][HID] bf16, Wd [DIM][HID] bf16, Out [M][DIM] f32
__global__ __launch_bounds__(256, 2) void gemm_down(
    const unsigned short* __restrict__ Hb,
    const unsigned short* __restrict__ Wd,
    float* __restrict__ Out, int M)
{
    __shared__ __attribute__((aligned(16))) unsigned short As[BM * BK];
    __shared__ __attribute__((aligned(16))) unsigned short Bs[BN * BK];

    const int tid  = threadIdx.x;
    const int lane = tid & 63;
    const int wid  = tid >> 6;
    const int wr   = wid >> 1, wc = wid & 1;
    const int m0 = blockIdx.x * BM;
    const int n0 = blockIdx.y * BN;

    const int idx0 = tid, idx1 = tid + 256;
    const int r0 = idx0 >> 2, c0 = (idx0 & 3) << 3;
    const int r1 = idx1 >> 2, c1 = (idx1 & 3) << 3;

    const unsigned short* A0 = Hb + (size_t)(m0 + r0) * HID + c0;
    const unsigned short* A1 = Hb + (size_t)(m0 + r1) * HID + c1;
    const unsigned short* B0 = Wd + (size_t)(n0 + r0) * HID + c0;
    const unsigned short* B1 = Wd + (size_t)(n0 + r1) * HID + c1;

    f32x4 acc[4][4] = {};

    const int lr = lane & 15;
    const int kr = (lane >> 4) << 3;

    for (int k0 = 0; k0 < HID; k0 += BK) {
        gload16(A0 + k0, &As[idx0 * 8]);
        gload16(A1 + k0, &As[idx1 * 8]);
        gload16(B0 + k0, &Bs[idx0 * 8]);
        gload16(B1 + k0, &Bs[idx1 * 8]);
        __syncthreads();

        short8 a[4], b[4];
        #pragma unroll
        for (int i = 0; i < 4; ++i)
            a[i] = *(const short8*)&As[(wr * 64 + i * 16 + lr) * BK + kr];
        #pragma unroll
        for (int i = 0; i < 4; ++i)
            b[i] = *(const short8*)&Bs[(wc * 64 + i * 16 + lr) * BK + kr];

        #pragma unroll
        for (int i = 0; i < 4; ++i) {
            #pragma unroll
            for (int j = 0; j < 4; ++j) {
                acc[i][j] = __builtin_amdgcn_mfma_f32_16x16x32_bf16(a[i], b[j], acc[i][j], 0, 0, 0);
            }
        }
        __syncthreads();
    }

    const int lg = lane >> 4;
    #pragma unroll
    for (int i = 0; i < 4; ++i) {
        #pragma unroll
        for (int j = 0; j < 4; ++j) {
            #pragma unroll
            for (int e = 0; e < 4; ++e) {
                int row = m0 + wr * 64 + i * 16 + lg * 4 + e;
                int col = n0 + wc * 64 + j * 16 + lr;
                Out[(size_t)row * DIM + col] = acc[i][j][e];
            }
        }
    }
}

extern "C" void kernel_launch(void* const* d_in, const int* in_sizes, int n_in,
                              void* d_out, int out_size, void* d_ws, size_t ws_size,
                              hipStream_t stream) {
    const float* x      = (const float*)d_in[0];
    const int* wq_gate  = (const int*)d_in[1];
    const float* s_gate = (const float*)d_in[2];
    const int* wq_up    = (const int*)d_in[3];
    const float* s_up   = (const float*)d_in[4];
    const int* wq_down  = (const int*)d_in[5];
    const float* s_down = (const float*)d_in[6];
    float* out = (float*)d_out;

    const int M = in_sizes[0] / DIM;  // 8192

    // workspace layout (bytes):
    //   xb : M*DIM*2        = 33,554,432
    //   w1 : HID*DIM*2      = 23,068,672   (gate weights; reused for down weights)
    //   w2 : HID*DIM*2      = 23,068,672   (up weights)
    //   h  : M*HID*2        = 92,274,688
    char* ws = (char*)d_ws;
    unsigned short* xb = (unsigned short*)ws;
    unsigned short* w1 = (unsigned short*)(ws + (size_t)M * DIM * 2);
    unsigned short* w2 = w1 + (size_t)HID * DIM;
    unsigned short* h  = w2 + (size_t)HID * DIM;

    cast_f32_bf16<<<2048, 256, 0, stream>>>(x, xb, (long)M * DIM);
    dequant_bf16<<<2048, 256, 0, stream>>>(wq_gate, s_gate, w1, (long)HID * DIM, DIM);
    dequant_bf16<<<2048, 256, 0, stream>>>(wq_up, s_up, w2, (long)HID * DIM, DIM);

    gemm_gateup<<<dim3(M / BM, HID / BN), 256, 0, stream>>>(xb, w1, w2, h, M);

    // reuse w1 for down weights (stream-ordered after gemm_gateup)
    dequant_bf16<<<2048, 256, 0, stream>>>(wq_down, s_down, w1, (long)DIM * HID, HID);

    gemm_down<<<dim3(M / BM, DIM / BN), 256, 0, stream>>>(h, w1, out, M);
}

// Round 2
// 587.653 us; speedup vs baseline: 1.1791x; 1.1791x over previous
//
#include <hip/hip_runtime.h>
#include <hip/hip_bf16.h>
#include <stdint.h>

#define DIM 2048
#define HID 5632

typedef __attribute__((ext_vector_type(8))) short short8;
typedef __attribute__((ext_vector_type(4))) float f32x4;
typedef __attribute__((ext_vector_type(4))) int int4v;
typedef __attribute__((ext_vector_type(4))) unsigned short ushort4v;

__device__ __forceinline__ unsigned short f32_to_bf16_rne(float f) {
    union { float f; unsigned u; } v; v.f = f;
    unsigned u = v.u;
    return (unsigned short)((u + 0x7FFFu + ((u >> 16) & 1u)) >> 16);
}

__device__ __forceinline__ void gload16(const void* g, void* l) {
    __builtin_amdgcn_global_load_lds(
        (const __attribute__((address_space(1))) void*)g,
        (__attribute__((address_space(3))) void*)l,
        16, 0, 0);
}

// ---- dequant down weights (plain row-major) ----
__global__ void dequant_plain(const int* __restrict__ wq, const float* __restrict__ scale,
                              unsigned short* __restrict__ out, long total, int cols) {
    long n4 = total >> 2;
    long stride = (long)gridDim.x * blockDim.x;
    for (long i = (long)blockIdx.x * blockDim.x + threadIdx.x; i < n4; i += stride) {
        int4v c = ((const int4v*)wq)[i];
        int row = (int)((i << 2) / cols);
        float s = scale[row];
        ushort4v o;
        o.x = f32_to_bf16_rne(((float)c.x - 128.0f) * s);
        o.y = f32_to_bf16_rne(((float)c.y - 128.0f) * s);
        o.z = f32_to_bf16_rne(((float)c.z - 128.0f) * s);
        o.w = f32_to_bf16_rne(((float)c.w - 128.0f) * s);
        ((ushort4v*)out)[i] = o;
    }
}

// ---- dequant gate+up into 16-row-interleaved W' [2*HID][DIM] ----
// W' rows [32j..32j+15] = gate rows [16j..16j+15]; [32j+16..32j+31] = up rows.
__global__ void dequant_gateup(const int* __restrict__ wg, const float* __restrict__ sg,
                               const int* __restrict__ wu, const float* __restrict__ su,
                               unsigned short* __restrict__ out) {
    const long n4 = (long)HID * DIM / 4;   // DIM/4 = 512 chunks per row
    long stride = (long)gridDim.x * blockDim.x;
    for (long i = (long)blockIdx.x * blockDim.x + threadIdx.x; i < n4; i += stride) {
        int r  = (int)(i >> 9);        // row (DIM/4 = 512 is pow2)
        int c4 = (int)(i & 511);
        int rp = ((r >> 4) << 5) + (r & 15);
        float s1 = sg[r], s2 = su[r];
        int4v g = ((const int4v*)wg)[i];
        int4v u = ((const int4v*)wu)[i];
        ushort4v og, ou;
        og.x = f32_to_bf16_rne(((float)g.x - 128.0f) * s1);
        og.y = f32_to_bf16_rne(((float)g.y - 128.0f) * s1);
        og.z = f32_to_bf16_rne(((float)g.z - 128.0f) * s1);
        og.w = f32_to_bf16_rne(((float)g.w - 128.0f) * s1);
        ou.x = f32_to_bf16_rne(((float)u.x - 128.0f) * s2);
        ou.y = f32_to_bf16_rne(((float)u.y - 128.0f) * s2);
        ou.z = f32_to_bf16_rne(((float)u.z - 128.0f) * s2);
        ou.w = f32_to_bf16_rne(((float)u.w - 128.0f) * s2);
        ((ushort4v*)out)[(long)rp * 512 + c4]        = og;
        ((ushort4v*)out)[(long)(rp + 16) * 512 + c4] = ou;
    }
}

// ---- x: f32 -> bf16 ----
__global__ void cast_f32_bf16(const float* __restrict__ in, unsigned short* __restrict__ out, long n) {
    long n4 = n >> 2;
    long stride = (long)gridDim.x * blockDim.x;
    for (long i = (long)blockIdx.x * blockDim.x + threadIdx.x; i < n4; i += stride) {
        f32x4 v = ((const f32x4*)in)[i];
        ushort4v o;
        o.x = f32_to_bf16_rne(v[0]);
        o.y = f32_to_bf16_rne(v[1]);
        o.z = f32_to_bf16_rne(v[2]);
        o.w = f32_to_bf16_rne(v[3]);
        ((ushort4v*)out)[i] = o;
    }
}

// =====================================================================
// 256x256-tile BK=64 double-buffered GEMM, counted-vmcnt schedule.
// LDS tiles [256][64] bf16, XOR swizzle: 16B-chunk index ^= (row&7)
// (linear global_load_lds dest + inverse-swizzled global src + swizzled read).
// 512 threads = 8 waves (2M x 4N), per-wave 128x64, acc[8][4] f32x4.
// =====================================================================

// ---- fused gate+up: H[M][HID] bf16 = silu(X@Wg^T)*(X@Wu^T), W' interleaved ----
__global__ __launch_bounds__(512, 2) void gemm_gateup(
    const unsigned short* __restrict__ X,
    const unsigned short* __restrict__ Wp,
    unsigned short* __restrict__ H)
{
    __shared__ __attribute__((aligned(16))) unsigned short As[2][256 * 64];
    __shared__ __attribute__((aligned(16))) unsigned short Bs[2][256 * 64];

    const int tid  = threadIdx.x;
    const int lane = tid & 63;
    const int wid  = tid >> 6;
    const int wr   = wid >> 2;    // 0..1
    const int wc   = wid & 3;     // 0..3
    const int m0   = blockIdx.x << 8;
    const int n0   = blockIdx.y << 8;
    const int lr   = lane & 15;
    const int kg   = lane >> 4;

    // staging geometry (kt-invariant): chunk q -> LDS linear, global pre-swizzled
    int srow[4], skc[4], sdst[4];
    #pragma unroll
    for (int l = 0; l < 4; ++l) {
        int q = l * 512 + tid;
        srow[l] = q >> 3;
        skc[l]  = (((q & 7) ^ ((q >> 3) & 7)) << 3);
        sdst[l] = q << 3;
    }

    auto STAGE = [&](int buf, int kt) {
        const int kk = kt << 6;
        #pragma unroll
        for (int l = 0; l < 4; ++l) {
            gload16(X  + (size_t)(m0 + srow[l]) * DIM + kk + skc[l], &As[buf][sdst[l]]);
            gload16(Wp + (size_t)(n0 + srow[l]) * DIM + kk + skc[l], &Bs[buf][sdst[l]]);
        }
    };

    f32x4 acc[8][4];
    #pragma unroll
    for (int m = 0; m < 8; ++m)
        #pragma unroll
        for (int n = 0; n < 4; ++n) acc[m][n] = (f32x4){0.f, 0.f, 0.f, 0.f};

    // frag read offsets: row&7 == lr&7 (m*16, n*16 are 0 mod 8)
    const int c0 = ((kg ^ (lr & 7)) << 3);
    const int c1 = (((4 + kg) ^ (lr & 7)) << 3);
    const int abase = (wr * 128 + lr) * 64;
    const int bbase = (wc * 64 + lr) * 64;

    STAGE(0, 0);
    STAGE(1, 1);

    const int NT = DIM / 64;  // 32
    for (int kt = 0; kt < NT; ++kt) {
        const int cur = kt & 1;
        if (kt < NT - 1) asm volatile("s_waitcnt vmcnt(8)" ::: "memory");
        else             asm volatile("s_waitcnt vmcnt(0)" ::: "memory");
        __builtin_amdgcn_s_barrier();
        __builtin_amdgcn_sched_barrier(0);

        const unsigned short* ap0 = &As[cur][abase + c0];
        const unsigned short* ap1 = &As[cur][abase + c1];
        const unsigned short* bp0 = &Bs[cur][bbase + c0];
        const unsigned short* bp1 = &Bs[cur][bbase + c1];

        short8 a0[8], a1[8], b0[4], b1[4];
        #pragma unroll
        for (int n = 0; n < 4; ++n) {
            b0[n] = *(const short8*)(bp0 + (n << 10));
            b1[n] = *(const short8*)(bp1 + (n << 10));
        }
        #pragma unroll
        for (int m = 0; m < 8; ++m) {
            a0[m] = *(const short8*)(ap0 + (m << 10));
            a1[m] = *(const short8*)(ap1 + (m << 10));
        }

        __builtin_amdgcn_s_setprio(1);
        #pragma unroll
        for (int m = 0; m < 8; ++m)
            #pragma unroll
            for (int n = 0; n < 4; ++n)
                acc[m][n] = __builtin_amdgcn_mfma_f32_16x16x32_bf16(a0[m], b0[n], acc[m][n], 0, 0, 0);
        __builtin_amdgcn_s_setprio(0);
        __builtin_amdgcn_s_setprio(1);
        #pragma unroll
        for (int m = 0; m < 8; ++m)
            #pragma unroll
            for (int n = 0; n < 4; ++n)
                acc[m][n] = __builtin_amdgcn_mfma_f32_16x16x32_bf16(a1[m], b1[n], acc[m][n], 0, 0, 0);
        __builtin_amdgcn_s_setprio(0);

        __builtin_amdgcn_sched_barrier(0);
        __builtin_amdgcn_s_barrier();
        __builtin_amdgcn_sched_barrier(0);
        if (kt + 2 < NT) STAGE(cur, kt + 2);
        __builtin_amdgcn_sched_barrier(0);
    }

    // epilogue: n even = gate frag, n odd = up frag (same H columns)
    const int lg = lane >> 4;
    #pragma unroll
    for (int m = 0; m < 8; ++m) {
        #pragma unroll
        for (int i = 0; i < 2; ++i) {
            f32x4 g = acc[m][2 * i], u = acc[m][2 * i + 1];
            const int col = (blockIdx.y << 7) + wc * 32 + i * 16 + lr;
            #pragma unroll
            for (int e = 0; e < 4; ++e) {
                const int row = m0 + wr * 128 + m * 16 + lg * 4 + e;
                float gv = g[e];
                float sg = gv / (1.0f + __expf(-gv));
                H[(size_t)row * HID + col] = f32_to_bf16_rne(sg * u[e]);
            }
        }
    }
}

// ---- down: Out[M][DIM] f32 = H @ Wd^T ----
__global__ __launch_bounds__(512, 2) void gemm_down(
    const unsigned short* __restrict__ Hb,
    const unsigned short* __restrict__ Wd,
    float* __restrict__ Out)
{
    __shared__ __attribute__((aligned(16))) unsigned short As[2][256 * 64];
    __shared__ __attribute__((aligned(16))) unsigned short Bs[2][256 * 64];

    const int tid  = threadIdx.x;
    const int lane = tid & 63;
    const int wid  = tid >> 6;
    const int wr   = wid >> 2;
    const int wc   = wid & 3;
    const int m0   = blockIdx.x << 8;
    const int n0   = blockIdx.y << 8;
    const int lr   = lane & 15;
    const int kg   = lane >> 4;

    int srow[4], skc[4], sdst[4];
    #pragma unroll
    for (int l = 0; l < 4; ++l) {
        int q = l * 512 + tid;
        srow[l] = q >> 3;
        skc[l]  = (((q & 7) ^ ((q >> 3) & 7)) << 3);
        sdst[l] = q << 3;
    }

    auto STAGE = [&](int buf, int kt) {
        const int kk = kt << 6;
        #pragma unroll
        for (int l = 0; l < 4; ++l) {
            gload16(Hb + (size_t)(m0 + srow[l]) * HID + kk + skc[l], &As[buf][sdst[l]]);
            gload16(Wd + (size_t)(n0 + srow[l]) * HID + kk + skc[l], &Bs[buf][sdst[l]]);
        }
    };

    f32x4 acc[8][4];
    #pragma unroll
    for (int m = 0; m < 8; ++m)
        #pragma unroll
        for (int n = 0; n < 4; ++n) acc[m][n] = (f32x4){0.f, 0.f, 0.f, 0.f};

    const int c0 = ((kg ^ (lr & 7)) << 3);
    const int c1 = (((4 + kg) ^ (lr & 7)) << 3);
    const int abase = (wr * 128 + lr) * 64;
    const int bbase = (wc * 64 + lr) * 64;

    STAGE(0, 0);
    STAGE(1, 1);

    const int NT = HID / 64;  // 88
    for (int kt = 0; kt < NT; ++kt) {
        const int cur = kt & 1;
        if (kt < NT - 1) asm volatile("s_waitcnt vmcnt(8)" ::: "memory");
        else             asm volatile("s_waitcnt vmcnt(0)" ::: "memory");
        __builtin_amdgcn_s_barrier();
        __builtin_amdgcn_sched_barrier(0);

        const unsigned short* ap0 = &As[cur][abase + c0];
        const unsigned short* ap1 = &As[cur][abase + c1];
        const unsigned short* bp0 = &Bs[cur][bbase + c0];
        const unsigned short* bp1 = &Bs[cur][bbase + c1];

        short8 a0[8], a1[8], b0[4], b1[4];
        #pragma unroll
        for (int n = 0; n < 4; ++n) {
            b0[n] = *(const short8*)(bp0 + (n << 10));
            b1[n] = *(const short8*)(bp1 + (n << 10));
        }
        #pragma unroll
        for (int m = 0; m < 8; ++m) {
            a0[m] = *(const short8*)(ap0 + (m << 10));
            a1[m] = *(const short8*)(ap1 + (m << 10));
        }

        __builtin_amdgcn_s_setprio(1);
        #pragma unroll
        for (int m = 0; m < 8; ++m)
            #pragma unroll
            for (int n = 0; n < 4; ++n)
                acc[m][n] = __builtin_amdgcn_mfma_f32_16x16x32_bf16(a0[m], b0[n], acc[m][n], 0, 0, 0);
        __builtin_amdgcn_s_setprio(0);
        __builtin_amdgcn_s_setprio(1);
        #pragma unroll
        for (int m = 0; m < 8; ++m)
            #pragma unroll
            for (int n = 0; n < 4; ++n)
                acc[m][n] = __builtin_amdgcn_mfma_f32_16x16x32_bf16(a1[m], b1[n], acc[m][n], 0, 0, 0);
        __builtin_amdgcn_s_setprio(0);

        __builtin_amdgcn_sched_barrier(0);
        __builtin_amdgcn_s_barrier();
        __builtin_amdgcn_sched_barrier(0);
        if (kt + 2 < NT) STAGE(cur, kt + 2);
        __builtin_amdgcn_sched_barrier(0);
    }

    const int lg = lane >> 4;
    #pragma unroll
    for (int m = 0; m < 8; ++m) {
        #pragma unroll
        for (int n = 0; n < 4; ++n) {
            const int col = n0 + wc * 64 + n * 16 + lr;
            #pragma unroll
            for (int e = 0; e < 4; ++e) {
                const int row = m0 + wr * 128 + m * 16 + lg * 4 + e;
                Out[(size_t)row * DIM + col] = acc[m][n][e];
            }
        }
    }
}

extern "C" void kernel_launch(void* const* d_in, const int* in_sizes, int n_in,
                              void* d_out, int out_size, void* d_ws, size_t ws_size,
                              hipStream_t stream) {
    const float* x      = (const float*)d_in[0];
    const int* wq_gate  = (const int*)d_in[1];
    const float* s_gate = (const float*)d_in[2];
    const int* wq_up    = (const int*)d_in[3];
    const float* s_up   = (const float*)d_in[4];
    const int* wq_down  = (const int*)d_in[5];
    const float* s_down = (const float*)d_in[6];
    float* out = (float*)d_out;

    const int M = in_sizes[0] / DIM;  // 8192

    // ws layout (elems, bf16): xb [M*DIM] | wgu [2*HID*DIM] (down weights alias this) | h [M*HID]
    unsigned short* xb  = (unsigned short*)d_ws;
    unsigned short* wgu = xb + (size_t)M * DIM;
    unsigned short* h   = wgu + (size_t)2 * HID * DIM;

    cast_f32_bf16<<<2048, 256, 0, stream>>>(x, xb, (long)M * DIM);
    dequant_gateup<<<2048, 256, 0, stream>>>(wq_gate, s_gate, wq_up, s_up, wgu);

    gemm_gateup<<<dim3(M / 256, (2 * HID) / 256), 512, 0, stream>>>(xb, wgu, h);

    // reuse wgu region for down weights (stream-ordered)
    dequant_plain<<<2048, 256, 0, stream>>>(wq_down, s_down, wgu, (long)DIM * HID, HID);

    gemm_down<<<dim3(M / 256, DIM / 256), 512, 0, stream>>>(h, wgu, out);
}